// Round 7
// baseline (793.842 us; speedup 1.0000x reference)
//
#include <hip/hip_runtime.h>
#include <hip/hip_bf16.h>
#include <hip/hip_fp16.h>

// Problem dims
#define A_DIM 4608   // C*9 patch-feature rows
#define L_DIM 4096   // (H/3)*(W/3) spatial columns
#define CH    512
#define H_DIM 192
#define W_DIM 192

// GEMM tile: 128x192 block, 64x96 wave tile. R14: WAVE-PRIVATE staging,
// BK=16, double buffer, ZERO barriers in the K-loop.
#define BM 128
#define BN 192
#define BK 16        // 2 kchunks of 8 halves per stage
#define NS (L_DIM / BK)

#define CPB 32       // prep: channels per block

typedef _Float16 half8 __attribute__((ext_vector_type(8)));
typedef float   floatx4 __attribute__((ext_vector_type(4)));
typedef float   floatx16 __attribute__((ext_vector_type(16)));

// ---------------------------------------------------------------------------
// Pass 1: unfold(x) -> k-chunk-major f16 hi/lo split + global sum-of-squares
// accumulation (ss arrays pre-zeroed). 8-lane shuffle reduce + one global
// atomic per (c_l, q).
// Global layout: U[(l>>3)*A_DIM + a][8] (chunk-major; GEMM staging contiguous
// and conflict-free — verified: GEMM SQ_LDS_BANK_CONFLICT = 0).
// ---------------------------------------------------------------------------
__global__ __launch_bounds__(256) void prep_kernel(
    const float* __restrict__ x0, const float* __restrict__ x1,
    _Float16* __restrict__ Uhi0, _Float16* __restrict__ Ulo0,
    _Float16* __restrict__ Uhi1, _Float16* __restrict__ Ulo1,
    float* __restrict__ ss0, float* __restrict__ ss1) {
  const int which = blockIdx.z;
  const float* __restrict__ x = which ? x1 : x0;
  _Float16* __restrict__ Uhi = which ? Uhi1 : Uhi0;
  _Float16* __restrict__ Ulo = which ? Ulo1 : Ulo0;
  float* __restrict__ ssg = which ? ss1 : ss0;

  const int ph = blockIdx.y;            // 0..63
  const int c0 = blockIdx.x * CPB;      // channel group base
  const int abase = blockIdx.x * (CPB * 9);

  __shared__ _Float16 sHi[CPB * 9 * 8 * 8];  // 288 rows x 8 chunks x 8 halves
  __shared__ _Float16 sLo[CPB * 9 * 8 * 8];

  const int t = threadIdx.x;

  // ---- phase 1: read input, assemble 16B chunks in regs, stage in LDS
  const int c_l = t >> 3;               // 0..31
  const int s = t & 7;                  // chunk index this thread owns
  const float* __restrict__ rowbase =
      x + ((size_t)(c0 + c_l) * H_DIM + 3 * ph) * W_DIM + s * 24;
  float ssp[9] = {0.f, 0.f, 0.f, 0.f, 0.f, 0.f, 0.f, 0.f, 0.f};

#pragma unroll
  for (int kh = 0; kh < 3; ++kh) {
    const float* __restrict__ rp = rowbase + kh * W_DIM;
    floatx4 v4[6];
#pragma unroll
    for (int i = 0; i < 6; ++i) v4[i] = *(const floatx4*)(rp + i * 4);
    half8 hv[3], lv[3];
#pragma unroll
    for (int i = 0; i < 6; ++i)
#pragma unroll
      for (int j = 0; j < 4; ++j) {
        const int m = i * 4 + j;        // 0..23
        const int kw = m % 3, e = m / 3;
        const float v = v4[i][j];
        ssp[kh * 3 + kw] += v * v;
        const _Float16 h = (_Float16)v;
        hv[kw][e] = h;
        lv[kw][e] = (_Float16)(v - (float)h);
      }
#pragma unroll
    for (int kw = 0; kw < 3; ++kw) {
      const int a_l = c_l * 9 + kh * 3 + kw;
      const int addr = (a_l * 8 + (s ^ (a_l & 7))) * 8;  // XOR-swizzled chunk
      *(half8*)&sHi[addr] = hv[kw];
      *(half8*)&sLo[addr] = lv[kw];
    }
  }
  // ---- norm accumulation: 8-lane shuffle reduce over s, one global atomic
#pragma unroll
  for (int q = 0; q < 9; ++q) {
    float v = ssp[q];
    v += __shfl_down(v, 4, 8);
    v += __shfl_down(v, 2, 8);
    v += __shfl_down(v, 1, 8);
    if (s == 0) atomicAdd(&ssg[abase + c_l * 9 + q], v);
  }
  __syncthreads();

  // ---- phase 2: coalesced global writes (consecutive t = consecutive a)
#pragma unroll
  for (int i = 0; i < 9; ++i) {
    const int idx = i * 256 + t;        // 0..2303
    const int c8 = idx / 288;
    const int a_l = idx - c8 * 288;
    const int addr = (a_l * 8 + (c8 ^ (a_l & 7))) * 8;
    const size_t g = ((size_t)(ph * 8 + c8) * A_DIM + abase + a_l) * 8;
    *(half8*)&Uhi[g] = *(const half8*)&sHi[addr];
    *(half8*)&Ulo[g] = *(const half8*)&sLo[addr];
  }
}

// ---------------------------------------------------------------------------
// Pass 2: D[i,j] = sty_i . img_j, 3-term f16 split, 32x32x16 MFMA, 128x192
// tile, 64x96 wave tile.
//
// R14 (wave-private, barrier-free): six barrier-per-K-step schedules
// (R2/R4/R5/R6 variants) all pinned at 49-54% MfmaUtil — the per-step
// s_barrier re-converges all waves, so read-bursts and MFMA-bursts stay
// time-aligned across waves and the LDS port and MFMA pipe serialize
// (~2560 + ~2300 cyc ≈ 5377 measured per macro-step). Here each wave
// stages EXACTLY the LDS it reads (its 64 A rows + 96 B rows, hi+lo;
// 10 KB/wave/stage, x2 buffers x4 waves = 80 KB, 2 blocks/CU), so
// producer == consumer per wave and the per-wave vmcnt is the only sync:
//   lgkmcnt(0)                 -- my prev-step ds_reads done (free)
//   ISSUE(other buf, ks+1)     -- 10 GLDS (queue never drains)
//   vmcnt(10)                  -- my stage-ks writes landed
//   10 ds_read_b128 + 18 MFMA  -- compiler-scheduled
// NO s_barrier anywhere: waves free-run and self-skew, so one wave's reads
// overlap another's MFMAs. LDS cost: A,B duplicated across wave pairs
// (port has headroom); duplicate global reads are same-line L2 hits.
// Per-acc-element accumulation order (per step: hh, hl, lh; K ascending)
// identical to R2 -> bit-identical output.
//
// Block swizzle (1-D grid, 864 = 3*288 blocks): id -> (bx,by); XCD
// (heuristic id%8) pins one B col-tile (3 MB, fits 4 MB XCD-L2) across all
// 36 by-steps.
// ---------------------------------------------------------------------------
#define GLDS(g, l)                                                          \
  __builtin_amdgcn_global_load_lds(                                        \
      (const __attribute__((address_space(1))) void*)(g),                   \
      (__attribute__((address_space(3))) void*)(l), 16, 0, 0)

#define MFMA_(A, B, C) __builtin_amdgcn_mfma_f32_32x32x16_f16(A, B, C, 0, 0, 0)

// Per-wave buffer layout (halves, 5120 per buffer):
//   Ah [0,1024):    (kc*64 + row)*8,  rows = wave's 64 A rows
//   Al [1024,2048)
//   Bh [2048,3584): (kc*96 + row)*8,  rows = wave's 96 B rows
//   Bl [3584,5120)
__global__ __launch_bounds__(256, 2) void gemm_max_kernel(
    const _Float16* __restrict__ Shi, const _Float16* __restrict__ Slo,
    const _Float16* __restrict__ Ihi, const _Float16* __restrict__ Ilo,
    const float* __restrict__ img_ss,
    unsigned long long* __restrict__ packed) {
  __shared__ _Float16 sm[4 * 2 * 5120];  // 80 KB -> 2 blocks/CU

  const int t = threadIdx.x;
  const int lane = t & 63, wv = t >> 6;
  const int wvr = wv >> 1, wvc = wv & 1;       // 2x2 waves, wave tile 64x96
  const int id = blockIdx.x;
  const int g = id / 288, r = id - g * 288;
  const int by = r >> 3, bx = g * 8 + (r & 7);
  const int row0 = by * BM;                    // sty rows (i)
  const int col0 = bx * BN;                    // img rows (j)
  const int l31 = lane & 31, hs = lane >> 5;
  const int wb = wv * 10240;                   // wave's LDS base (halves)

  floatx16 acc[2][3];
#pragma unroll
  for (int rf = 0; rf < 2; ++rf)
#pragma unroll
    for (int cf = 0; cf < 3; ++cf) acc[rf][cf] = (floatx16)0.f;

  const size_t CH8 = (size_t)A_DIM * 8;        // one kchunk plane, in halves

  // ---- wave-private staging addresses (global, per-lane; koff added/stage)
  const int rA = row0 + wvr * 64;              // wave's A row base
  const int rB = col0 + wvc * 96;              // wave's B row base
  const size_t gA0 = (size_t)(rA + lane) * 8;                     // kc0
  const size_t gA1 = CH8 + gA0;                                   // kc1
  const size_t gB0 = (size_t)(rB + lane) * 8;                     // kc0 r0-63
  const size_t gB1 = (lane < 32)                                  // split
                         ? (size_t)(rB + 64 + lane) * 8           // kc0 r64-95
                         : CH8 + (size_t)(rB + lane - 32) * 8;    // kc1 r0-31
  const size_t gB2 = CH8 + (size_t)(rB + 32 + lane) * 8;          // kc1 r32-95
  const int dl8 = lane * 8;                    // lane LDS offset (halves)

#define ISSUE(bb, koff)                                        \
  do {                                                         \
    GLDS(Shi + (koff) + gA0, &sm[wb + (bb) + dl8]);            \
    GLDS(Shi + (koff) + gA1, &sm[wb + (bb) + 512 + dl8]);      \
    GLDS(Slo + (koff) + gA0, &sm[wb + (bb) + 1024 + dl8]);     \
    GLDS(Slo + (koff) + gA1, &sm[wb + (bb) + 1536 + dl8]);     \
    GLDS(Ihi + (koff) + gB0, &sm[wb + (bb) + 2048 + dl8]);     \
    GLDS(Ihi + (koff) + gB1, &sm[wb + (bb) + 2560 + dl8]);     \
    GLDS(Ihi + (koff) + gB2, &sm[wb + (bb) + 3072 + dl8]);     \
    GLDS(Ilo + (koff) + gB0, &sm[wb + (bb) + 3584 + dl8]);     \
    GLDS(Ilo + (koff) + gB1, &sm[wb + (bb) + 4096 + dl8]);     \
    GLDS(Ilo + (koff) + gB2, &sm[wb + (bb) + 4608 + dl8]);     \
  } while (0)

  // fragment read offsets (halves, within wave buffer)
  const int aI = hs * 512 + l31 * 8;   // + rf*256; Ah +0, Al +1024
  const int bI = hs * 768 + l31 * 8;   // + cf*256; Bh +2048, Bl +3584

  // One K-step: reads buf at BOFF, prefetches stage KS+1 into the other buf.
#define KSTEP(BOFF, KS)                                                  \
  do {                                                                   \
    asm volatile("s_waitcnt lgkmcnt(0)" ::: "memory");                   \
    if ((KS) + 1 < NS) {                                                 \
      ISSUE(5120 - (BOFF), (size_t)((KS) + 1) * 2 * CH8);                \
      asm volatile("s_waitcnt vmcnt(10)" ::: "memory");                  \
    } else {                                                             \
      asm volatile("s_waitcnt vmcnt(0)" ::: "memory");                   \
    }                                                                    \
    const int base = wb + (BOFF);                                        \
    half8 ah[2], al[2], bh[3], bl[3];                                    \
    _Pragma("unroll")                                                    \
    for (int rf = 0; rf < 2; ++rf) {                                     \
      ah[rf] = *(const half8*)&sm[base + aI + rf * 256];                 \
      al[rf] = *(const half8*)&sm[base + 1024 + aI + rf * 256];          \
    }                                                                    \
    _Pragma("unroll")                                                    \
    for (int cf = 0; cf < 3; ++cf) {                                     \
      bh[cf] = *(const half8*)&sm[base + 2048 + bI + cf * 256];          \
      bl[cf] = *(const half8*)&sm[base + 3584 + bI + cf * 256];          \
    }                                                                    \
    _Pragma("unroll")                                                    \
    for (int rf = 0; rf < 2; ++rf)                                       \
      _Pragma("unroll")                                                  \
      for (int cf = 0; cf < 3; ++cf)                                     \
        acc[rf][cf] = MFMA_(ah[rf], bh[cf], acc[rf][cf]);                \
    _Pragma("unroll")                                                    \
    for (int rf = 0; rf < 2; ++rf)                                       \
      _Pragma("unroll")                                                  \
      for (int cf = 0; cf < 3; ++cf)                                     \
        acc[rf][cf] = MFMA_(ah[rf], bl[cf], acc[rf][cf]);                \
    _Pragma("unroll")                                                    \
    for (int rf = 0; rf < 2; ++rf)                                       \
      _Pragma("unroll")                                                  \
      for (int cf = 0; cf < 3; ++cf)                                     \
        acc[rf][cf] = MFMA_(al[rf], bh[cf], acc[rf][cf]);                \
  } while (0)

  // prologue: stage 0 into buf 0
  ISSUE(0, 0);
  for (int ks = 0; ks < NS; ks += 2) {  // NS = 256, even
    KSTEP(0, ks);
    KSTEP(5120, ks + 1);
  }

  // Epilogue: v[i,j] = rsqrt(img_ss[i]) * D[i,j]; column max+argmax
  // (first-index wins). 32x32 C/D: col=lane&31, row=(reg&3)+8*(reg>>2)+4*hs.
  float nrv[2][16];
#pragma unroll
  for (int rf = 0; rf < 2; ++rf) {
    const int base_i = row0 + wvr * 64 + rf * 32 + 4 * hs;
#pragma unroll
    for (int g2 = 0; g2 < 4; ++g2) {
      const floatx4 s4 = *(const floatx4*)&img_ss[base_i + 8 * g2];
#pragma unroll
      for (int r2 = 0; r2 < 4; ++r2) nrv[rf][g2 * 4 + r2] = 1.0f / sqrtf(s4[r2]);
    }
  }
#pragma unroll
  for (int cf = 0; cf < 3; ++cf) {
    const int j = col0 + wvc * 96 + cf * 32 + l31;
    float best = -3.4e38f;
    int bi = 0x7FFFFFFF;
#pragma unroll
    for (int rf = 0; rf < 2; ++rf) {
      const int base_i = row0 + wvr * 64 + rf * 32 + 4 * hs;
#pragma unroll
      for (int g2 = 0; g2 < 4; ++g2)
#pragma unroll
        for (int r2 = 0; r2 < 4; ++r2) {
          const int i = base_i + 8 * g2 + r2;
          const float v = acc[rf][cf][g2 * 4 + r2] * nrv[rf][g2 * 4 + r2];
          if (v > best) { best = v; bi = i; }  // ascending i => first wins
        }
    }
    const float ov = __shfl_xor(best, 32, 64);
    const int oi = __shfl_xor(bi, 32, 64);
    if (ov > best || (ov == best && oi < bi)) { best = ov; bi = oi; }
    if (hs == 0) {
      const unsigned u = __float_as_uint(best);
      const unsigned key = (u & 0x80000000u) ? ~u : (u | 0x80000000u);
      const unsigned long long pk =
          ((unsigned long long)key << 32) | (unsigned)(~(unsigned)bi);
      atomicMax(&packed[j], pk);
    }
  }
}

// ---------------------------------------------------------------------------
// Pass 3: decode packed, apply rsqrt(sty_ss[j]); out[0..A)=nearest,
// out[A..2A)=max_sim.
// ---------------------------------------------------------------------------
__global__ __launch_bounds__(256) void finalize_kernel(
    const unsigned long long* __restrict__ packed,
    const float* __restrict__ sty_ss, float* __restrict__ out) {
  const int j = blockIdx.x * 256 + threadIdx.x;
  if (j >= A_DIM) return;
  const unsigned long long p = packed[j];
  const unsigned key = (unsigned)(p >> 32);
  const unsigned u = (key & 0x80000000u) ? (key ^ 0x80000000u) : ~key;
  const float v = __uint_as_float(u);
  const int idx = (int)(~(unsigned)(p & 0xFFFFFFFFu));
  out[j] = (float)idx;
  out[A_DIM + j] = v * (1.0f / sqrtf(sty_ss[j]));
}

extern "C" void kernel_launch(void* const* d_in, const int* in_sizes, int n_in,
                              void* d_out, int out_size, void* d_ws, size_t ws_size,
                              hipStream_t stream) {
  const float* model = (const float*)d_in[0];  // img side
  const float* style = (const float*)d_in[1];  // sty side
  float* out = (float*)d_out;
  char* ws = (char*)d_ws;

  const size_t usz = (size_t)A_DIM * L_DIM * 2;  // one f16 matrix: 37,748,736 B
  _Float16* img_hi = (_Float16*)(ws);
  _Float16* img_lo = (_Float16*)(ws + usz);
  _Float16* sty_hi = (_Float16*)(ws + 2 * usz);
  _Float16* sty_lo = (_Float16*)(ws + 3 * usz);
  float* img_ss = (float*)(ws + 4 * usz);        // zeroed accumulators
  float* sty_ss = img_ss + A_DIM;
  unsigned long long* packed = (unsigned long long*)(img_ss + 2 * A_DIM);

  // zero ss accumulators (2*A*4 B) + packed (A*8 B) in one contiguous memset
  hipMemsetAsync(img_ss, 0, (size_t)A_DIM * 16, stream);
  prep_kernel<<<dim3(CH / CPB, H_DIM / 3, 2), 256, 0, stream>>>(
      model, style, img_hi, img_lo, sty_hi, sty_lo, img_ss, sty_ss);
  gemm_max_kernel<<<dim3((A_DIM / BM) * (A_DIM / BN)), 256, 0, stream>>>(
      sty_hi, sty_lo, img_hi, img_lo, img_ss, packed);
  finalize_kernel<<<18, 256, 0, stream>>>(packed, sty_ss, out);
}

// Round 8
// 676.292 us; speedup vs baseline: 1.1738x; 1.1738x over previous
//
#include <hip/hip_runtime.h>
#include <hip/hip_bf16.h>
#include <hip/hip_fp16.h>

// Problem dims
#define A_DIM 4608   // C*9 patch-feature rows
#define L_DIM 4096   // (H/3)*(W/3) spatial columns
#define CH    512
#define H_DIM 192
#define W_DIM 192

// GEMM tile: 128x192 block, 64x96 wave tile. R15: BK=16, block-staged LDS
// double buffer + REGISTER-pipelined fragments (read stage i+1 while MFMA
// on stage i) — breaks the same-stage read->use chain that serialized the
// LDS port and MFMA pipe in R1-R7.
#define BM 128
#define BN 192
#define BK 16        // 2 kchunks of 8 halves per stage
#define NS (L_DIM / BK)

#define CPB 32       // prep: channels per block

typedef _Float16 half8 __attribute__((ext_vector_type(8)));
typedef float   floatx4 __attribute__((ext_vector_type(4)));
typedef float   floatx16 __attribute__((ext_vector_type(16)));

// ---------------------------------------------------------------------------
// Pass 1: unfold(x) -> k-chunk-major f16 hi/lo split + global sum-of-squares
// accumulation (ss arrays pre-zeroed). 8-lane shuffle reduce + one global
// atomic per (c_l, q).
// Global layout: U[(l>>3)*A_DIM + a][8] (chunk-major; GEMM staging contiguous
// and conflict-free — verified: GEMM SQ_LDS_BANK_CONFLICT = 0).
// ---------------------------------------------------------------------------
__global__ __launch_bounds__(256) void prep_kernel(
    const float* __restrict__ x0, const float* __restrict__ x1,
    _Float16* __restrict__ Uhi0, _Float16* __restrict__ Ulo0,
    _Float16* __restrict__ Uhi1, _Float16* __restrict__ Ulo1,
    float* __restrict__ ss0, float* __restrict__ ss1) {
  const int which = blockIdx.z;
  const float* __restrict__ x = which ? x1 : x0;
  _Float16* __restrict__ Uhi = which ? Uhi1 : Uhi0;
  _Float16* __restrict__ Ulo = which ? Ulo1 : Ulo0;
  float* __restrict__ ssg = which ? ss1 : ss0;

  const int ph = blockIdx.y;            // 0..63
  const int c0 = blockIdx.x * CPB;      // channel group base
  const int abase = blockIdx.x * (CPB * 9);

  __shared__ _Float16 sHi[CPB * 9 * 8 * 8];  // 288 rows x 8 chunks x 8 halves
  __shared__ _Float16 sLo[CPB * 9 * 8 * 8];

  const int t = threadIdx.x;

  // ---- phase 1: read input, assemble 16B chunks in regs, stage in LDS
  const int c_l = t >> 3;               // 0..31
  const int s = t & 7;                  // chunk index this thread owns
  const float* __restrict__ rowbase =
      x + ((size_t)(c0 + c_l) * H_DIM + 3 * ph) * W_DIM + s * 24;
  float ssp[9] = {0.f, 0.f, 0.f, 0.f, 0.f, 0.f, 0.f, 0.f, 0.f};

#pragma unroll
  for (int kh = 0; kh < 3; ++kh) {
    const float* __restrict__ rp = rowbase + kh * W_DIM;
    floatx4 v4[6];
#pragma unroll
    for (int i = 0; i < 6; ++i) v4[i] = *(const floatx4*)(rp + i * 4);
    half8 hv[3], lv[3];
#pragma unroll
    for (int i = 0; i < 6; ++i)
#pragma unroll
      for (int j = 0; j < 4; ++j) {
        const int m = i * 4 + j;        // 0..23
        const int kw = m % 3, e = m / 3;
        const float v = v4[i][j];
        ssp[kh * 3 + kw] += v * v;
        const _Float16 h = (_Float16)v;
        hv[kw][e] = h;
        lv[kw][e] = (_Float16)(v - (float)h);
      }
#pragma unroll
    for (int kw = 0; kw < 3; ++kw) {
      const int a_l = c_l * 9 + kh * 3 + kw;
      const int addr = (a_l * 8 + (s ^ (a_l & 7))) * 8;  // XOR-swizzled chunk
      *(half8*)&sHi[addr] = hv[kw];
      *(half8*)&sLo[addr] = lv[kw];
    }
  }
  // ---- norm accumulation: 8-lane shuffle reduce over s, one global atomic
#pragma unroll
  for (int q = 0; q < 9; ++q) {
    float v = ssp[q];
    v += __shfl_down(v, 4, 8);
    v += __shfl_down(v, 2, 8);
    v += __shfl_down(v, 1, 8);
    if (s == 0) atomicAdd(&ssg[abase + c_l * 9 + q], v);
  }
  __syncthreads();

  // ---- phase 2: coalesced global writes (consecutive t = consecutive a)
#pragma unroll
  for (int i = 0; i < 9; ++i) {
    const int idx = i * 256 + t;        // 0..2303
    const int c8 = idx / 288;
    const int a_l = idx - c8 * 288;
    const int addr = (a_l * 8 + (c8 ^ (a_l & 7))) * 8;
    const size_t g = ((size_t)(ph * 8 + c8) * A_DIM + abase + a_l) * 8;
    *(half8*)&Uhi[g] = *(const half8*)&sHi[addr];
    *(half8*)&Ulo[g] = *(const half8*)&sLo[addr];
  }
}

// ---------------------------------------------------------------------------
// Pass 2: D[i,j] = sty_i . img_j, 3-term f16 split, 32x32x16 MFMA, 128x192
// tile, 64x96 wave tile.
//
// R15 (register-pipelined): R1-R7 all had the wave execute
// [ds_reads(stage i)] -> lgkm wait -> [MFMAs(stage i)] — a same-stage
// dependency that, with barrier-released waves, makes the CU alternate
// port-saturated read bursts and MFMA bursts (measured: LDS cyc + MFMA cyc
// ~= wall, MfmaUtil pinned 49-54%). Here fragments are double-buffered in
// REGISTERS: each window does MFMAs on pre-loaded frags(i) while issuing
// ds_reads for frags(i+1), which have no consumer until the next window —
// the scheduler interleaves them under the 32-cyc MFMA pipe occupancy.
// Per step:
//   ISSUE(buf[i&1], stage i+2)   -- 5 GLDS; overwrites stage i (read-done
//                                   enforced by prior lgkm0+barrier)
//   vmcnt(5) [vmcnt(0) at tail]  -- stage i+1 landed; queue never drains
//   s_barrier                    -- stage i+1 visible to all waves
//   FREAD frags(i+1) <- buf[(i+1)&1]   (10 ds_read_b128, no consumer yet)
//   MM18 on frags(i)                   (independent -> true overlap)
//   lgkm0; s_barrier             -- all reads done before next overwrite
// Accumulation order per acc element (hh, hl, lh per 16-K step, ascending)
// identical to R6 -> bit-identical output. Staging decomposition = R6's
// verified 5-GLDS pattern (2 A + 3 B, wave-uniform LDS bases + lane*16B).
//
// Block swizzle (1-D grid, 864 = 3*288 blocks): id -> (bx,by); XCD
// (heuristic id%8) pins one B col-tile (3 MB, fits 4 MB XCD-L2) across all
// 36 by-steps.
// ---------------------------------------------------------------------------
#define GLDS(g, l)                                                          \
  __builtin_amdgcn_global_load_lds(                                        \
      (const __attribute__((address_space(1))) void*)(g),                   \
      (__attribute__((address_space(3))) void*)(l), 16, 0, 0)

#define MFMA_(A, B, C) __builtin_amdgcn_mfma_f32_32x32x16_f16(A, B, C, 0, 0, 0)

// Per-buffer layout (halves, 10240 per buffer = 20 KB):
//   Ah [0,2048)  Al [2048,4096)  Bh [4096,7168)  Bl [7168,10240)
// A: 2 kc x 128 rows x 8; B: 2 kc x 192 rows x 8.
__global__ __launch_bounds__(256, 2) void gemm_max_kernel(
    const _Float16* __restrict__ Shi, const _Float16* __restrict__ Slo,
    const _Float16* __restrict__ Ihi, const _Float16* __restrict__ Ilo,
    const float* __restrict__ img_ss,
    unsigned long long* __restrict__ packed) {
  __shared__ _Float16 sm[2 * 10240];  // 40 KB -> 2 blocks/CU (LDS-wise more)

  const int t = threadIdx.x;
  const int lane = t & 63, wv = t >> 6;
  const int wvr = wv >> 1, wvc = wv & 1;       // 2x2 waves, wave tile 64x96
  const int id = blockIdx.x;
  const int g = id / 288, r = id - g * 288;
  const int by = r >> 3, bx = g * 8 + (r & 7);
  const int row0 = by * BM;                    // sty rows (i)
  const int col0 = bx * BN;                    // img rows (j)
  const int l31 = lane & 31, hs = lane >> 5;

  floatx16 acc[2][3];
#pragma unroll
  for (int rf = 0; rf < 2; ++rf)
#pragma unroll
    for (int cf = 0; cf < 3; ++cf) acc[rf][cf] = (floatx16)0.f;

  const size_t CH8 = (size_t)A_DIM * 8;        // one kchunk plane, in halves

  // ---- staging decomposition (R6-verified). A: thread t -> (kc=t>>7,
  // row=t&127). B: 768 chunks (hi 384 then lo 384), c = i*256+t.
  const size_t aOff = (size_t)(t >> 7) * CH8 + (size_t)(row0 + (t & 127)) * 8;
  const int aDst = t * 8;
  const size_t bG0 = (size_t)(t / 192) * CH8 + (size_t)(col0 + (t % 192)) * 8;
  const int bD0 = 4096 + t * 8;
  const int c1 = 256 + t;
  const int mat1 = (c1 >= 384) ? 1 : 0;        // uniform per wave
  const int rem1 = c1 - mat1 * 384;
  const _Float16* __restrict__ bP1 = mat1 ? Ilo : Ihi;
  const size_t bG1 =
      (size_t)(rem1 / 192) * CH8 + (size_t)(col0 + (rem1 % 192)) * 8;
  const int bD1 = 4096 + mat1 * 3072 + rem1 * 8;
  const int rem2 = 128 + t;
  const size_t bG2 =
      (size_t)(rem2 / 192) * CH8 + (size_t)(col0 + (rem2 % 192)) * 8;
  const int bD2 = 7168 + rem2 * 8;

#define ISSUE(BB, koff)                                  \
  do {                                                   \
    GLDS(Shi + (koff) + aOff, &sm[(BB) + aDst]);         \
    GLDS(Slo + (koff) + aOff, &sm[(BB) + 2048 + aDst]);  \
    GLDS(Ihi + (koff) + bG0, &sm[(BB) + bD0]);           \
    GLDS(bP1 + (koff) + bG1, &sm[(BB) + bD1]);           \
    GLDS(Ilo + (koff) + bG2, &sm[(BB) + bD2]);           \
  } while (0)

  // fragment read offsets (halves)
  const int aI = hs * 1024 + (wvr * 64 + l31) * 8;   // + rf*256
  const int bI = hs * 1536 + (wvc * 96 + l31) * 8;   // + cf*256

#define FREAD(AH, AL, BH, BL, BB)                              \
  do {                                                         \
    _Pragma("unroll")                                          \
    for (int rf = 0; rf < 2; ++rf) {                           \
      AH[rf] = *(const half8*)&sm[(BB) + aI + rf * 256];       \
      AL[rf] = *(const half8*)&sm[(BB) + 2048 + aI + rf * 256];\
    }                                                          \
    _Pragma("unroll")                                          \
    for (int cf = 0; cf < 3; ++cf) {                           \
      BH[cf] = *(const half8*)&sm[(BB) + 4096 + bI + cf * 256];\
      BL[cf] = *(const half8*)&sm[(BB) + 7168 + bI + cf * 256];\
    }                                                          \
  } while (0)

  // 18 MFMAs; per-acc order hh, hl, lh (matches R6 -> bit-identical)
#define MM18(AH, AL, BH, BL)                                   \
  do {                                                         \
    _Pragma("unroll")                                          \
    for (int rf = 0; rf < 2; ++rf)                             \
      _Pragma("unroll")                                        \
      for (int cf = 0; cf < 3; ++cf)                           \
        acc[rf][cf] = MFMA_(AH[rf], BH[cf], acc[rf][cf]);      \
    _Pragma("unroll")                                          \
    for (int rf = 0; rf < 2; ++rf)                             \
      _Pragma("unroll")                                        \
      for (int cf = 0; cf < 3; ++cf)                           \
        acc[rf][cf] = MFMA_(AH[rf], BL[cf], acc[rf][cf]);      \
    _Pragma("unroll")                                          \
    for (int rf = 0; rf < 2; ++rf)                             \
      _Pragma("unroll")                                        \
      for (int cf = 0; cf < 3; ++cf)                           \
        acc[rf][cf] = MFMA_(AL[rf], BH[cf], acc[rf][cf]);      \
  } while (0)

#define BARRIER asm volatile("s_barrier" ::: "memory")
#define LGKM0 asm volatile("s_waitcnt lgkmcnt(0)" ::: "memory")

  half8 ahA[2], alA[2], bhA[3], blA[3];   // frag set A (even stages)
  half8 ahB[2], alB[2], bhB[3], blB[3];   // frag set B (odd stages)

  // prologue: stages 0,1 in flight; load frags(0) into set A
  ISSUE(0, 0);
  ISSUE(10240, 2 * CH8);
  asm volatile("s_waitcnt vmcnt(5)" ::: "memory");  // stage 0 landed
  BARRIER;
  FREAD(ahA, alA, bhA, blA, 0);
  LGKM0;
  BARRIER;  // all waves read buf0 -> iter 0 may overwrite it

  for (int ks = 0; ks < NS; ks += 2) {
    // ---- even step: compute frags A (stage ks), read frags B (ks+1)
    if (ks + 2 < NS) {
      ISSUE(0, (size_t)(ks + 2) * 2 * CH8);
      asm volatile("s_waitcnt vmcnt(5)" ::: "memory");  // stage ks+1 landed
    } else {
      asm volatile("s_waitcnt vmcnt(0)" ::: "memory");
    }
    BARRIER;  // stage ks+1 visible to all
    FREAD(ahB, alB, bhB, blB, 10240);  // no consumer until next step
    MM18(ahA, alA, bhA, blA);          // overlaps with the reads above
    LGKM0;
    BARRIER;  // all waves' reads of buf1 done -> next ISSUE may overwrite

    // ---- odd step: compute frags B (stage ks+1), read frags A (ks+2)
    const bool more = (ks + 2 < NS);
    if (ks + 3 < NS) {
      ISSUE(10240, (size_t)(ks + 3) * 2 * CH8);
      asm volatile("s_waitcnt vmcnt(5)" ::: "memory");  // stage ks+2 landed
    } else {
      asm volatile("s_waitcnt vmcnt(0)" ::: "memory");
    }
    BARRIER;
    if (more) FREAD(ahA, alA, bhA, blA, 0);
    MM18(ahB, alB, bhB, blB);
    LGKM0;
    BARRIER;
  }

  // Epilogue: v[i,j] = rsqrt(img_ss[i]) * D[i,j]; column max+argmax
  // (first-index wins). 32x32 C/D: col=lane&31, row=(reg&3)+8*(reg>>2)+4*hs.
  float nrv[2][16];
#pragma unroll
  for (int rf = 0; rf < 2; ++rf) {
    const int base_i = row0 + wvr * 64 + rf * 32 + 4 * hs;
#pragma unroll
    for (int g2 = 0; g2 < 4; ++g2) {
      const floatx4 s4 = *(const floatx4*)&img_ss[base_i + 8 * g2];
#pragma unroll
      for (int r2 = 0; r2 < 4; ++r2) nrv[rf][g2 * 4 + r2] = 1.0f / sqrtf(s4[r2]);
    }
  }
#pragma unroll
  for (int cf = 0; cf < 3; ++cf) {
    const int j = col0 + wvc * 96 + cf * 32 + l31;
    float best = -3.4e38f;
    int bi = 0x7FFFFFFF;
#pragma unroll
    for (int rf = 0; rf < 2; ++rf) {
      const int base_i = row0 + wvr * 64 + rf * 32 + 4 * hs;
#pragma unroll
      for (int g2 = 0; g2 < 4; ++g2)
#pragma unroll
        for (int r2 = 0; r2 < 4; ++r2) {
          const int i = base_i + 8 * g2 + r2;
          const float v = acc[rf][cf][g2 * 4 + r2] * nrv[rf][g2 * 4 + r2];
          if (v > best) { best = v; bi = i; }  // ascending i => first wins
        }
    }
    const float ov = __shfl_xor(best, 32, 64);
    const int oi = __shfl_xor(bi, 32, 64);
    if (ov > best || (ov == best && oi < bi)) { best = ov; bi = oi; }
    if (hs == 0) {
      const unsigned u = __float_as_uint(best);
      const unsigned key = (u & 0x80000000u) ? ~u : (u | 0x80000000u);
      const unsigned long long pk =
          ((unsigned long long)key << 32) | (unsigned)(~(unsigned)bi);
      atomicMax(&packed[j], pk);
    }
  }
}

// ---------------------------------------------------------------------------
// Pass 3: decode packed, apply rsqrt(sty_ss[j]); out[0..A)=nearest,
// out[A..2A)=max_sim.
// ---------------------------------------------------------------------------
__global__ __launch_bounds__(256) void finalize_kernel(
    const unsigned long long* __restrict__ packed,
    const float* __restrict__ sty_ss, float* __restrict__ out) {
  const int j = blockIdx.x * 256 + threadIdx.x;
  if (j >= A_DIM) return;
  const unsigned long long p = packed[j];
  const unsigned key = (unsigned)(p >> 32);
  const unsigned u = (key & 0x80000000u) ? (key ^ 0x80000000u) : ~key;
  const float v = __uint_as_float(u);
  const int idx = (int)(~(unsigned)(p & 0xFFFFFFFFu));
  out[j] = (float)idx;
  out[A_DIM + j] = v * (1.0f / sqrtf(sty_ss[j]));
}

extern "C" void kernel_launch(void* const* d_in, const int* in_sizes, int n_in,
                              void* d_out, int out_size, void* d_ws, size_t ws_size,
                              hipStream_t stream) {
  const float* model = (const float*)d_in[0];  // img side
  const float* style = (const float*)d_in[1];  // sty side
  float* out = (float*)d_out;
  char* ws = (char*)d_ws;

  const size_t usz = (size_t)A_DIM * L_DIM * 2;  // one f16 matrix: 37,748,736 B
  _Float16* img_hi = (_Float16*)(ws);
  _Float16* img_lo = (_Float16*)(ws + usz);
  _Float16* sty_hi = (_Float16*)(ws + 2 * usz);
  _Float16* sty_lo = (_Float16*)(ws + 3 * usz);
  float* img_ss = (float*)(ws + 4 * usz);        // zeroed accumulators
  float* sty_ss = img_ss + A_DIM;
  unsigned long long* packed = (unsigned long long*)(img_ss + 2 * A_DIM);

  // zero ss accumulators (2*A*4 B) + packed (A*8 B) in one contiguous memset
  hipMemsetAsync(img_ss, 0, (size_t)A_DIM * 16, stream);
  prep_kernel<<<dim3(CH / CPB, H_DIM / 3, 2), 256, 0, stream>>>(
      model, style, img_hi, img_lo, sty_hi, sty_lo, img_ss, sty_ss);
  gemm_max_kernel<<<dim3((A_DIM / BM) * (A_DIM / BN)), 256, 0, stream>>>(
      sty_hi, sty_lo, img_hi, img_lo, img_ss, packed);
  finalize_kernel<<<18, 256, 0, stream>>>(packed, sty_ss, out);
}